// Round 1
// baseline (4924.422 us; speedup 1.0000x reference)
//
#include <hip/hip_runtime.h>

#define ANG 9
#define HH 96
#define HUV 864
#define BB 2
#define PLANE_F (HUV*HUV)   // 746496
#define PLANE_A (HH*HH)     // 9216

// ---------------- SAI -> MacPI rearrange ----------------
__global__ __launch_bounds__(256) void k_macpi(const float* __restrict__ x, float* __restrict__ f) {
  int t = blockIdx.x * 256 + threadIdx.x;           // total BB*HUV*HUV = 1492992 (exact)
  int xx = t % HUV; int r = t / HUV; int y = r % HUV; int b = r / HUV;
  int u = y % ANG, i = y / ANG, v = xx % ANG, j = xx / ANG;
  f[t] = x[(b * HUV + u * HH + i) * HUV + v * HH + j];
}

// ---------------- dilated 3x3 feature conv (dil=pad=9), optional fused input BN+ReLU ----------------
template<int CIN, int COUT, bool AFF>
__global__ __launch_bounds__(256) void k_featconv(const float* __restrict__ in,
    const float* __restrict__ w, const float* __restrict__ sc, const float* __restrict__ sh,
    float* __restrict__ out) {
  int t = blockIdx.x * 256 + threadIdx.x;           // BB*HUV*HUV exact
  int x = t % HUV; int r = t / HUV; int y = r % HUV; int b = r / HUV;
  float acc[COUT];
  #pragma unroll
  for (int o = 0; o < COUT; o++) acc[o] = 0.f;
  #pragma unroll
  for (int c = 0; c < CIN; c++) {
    const float* ip = in + (b * CIN + c) * PLANE_F;
    float s  = AFF ? sc[c] : 1.f;
    float h2 = AFF ? sh[c] : 0.f;
    #pragma unroll
    for (int ky = 0; ky < 3; ky++) {
      int yy = y + 9 * ky - 9;
      #pragma unroll
      for (int kx = 0; kx < 3; kx++) {
        int xx = x + 9 * kx - 9;
        float v = 0.f;
        if ((unsigned)yy < (unsigned)HUV && (unsigned)xx < (unsigned)HUV) {
          v = ip[yy * HUV + xx];
          if (AFF) v = fmaxf(fmaf(v, s, h2), 0.f);
        }
        #pragma unroll
        for (int o = 0; o < COUT; o++)
          acc[o] = fmaf(w[(o * CIN + c) * 9 + ky * 3 + kx], v, acc[o]);
      }
    }
  }
  #pragma unroll
  for (int o = 0; o < COUT; o++)
    out[(b * COUT + o) * PLANE_F + y * HUV + x] = acc[o];
}

// ---------------- batch stats (big maps): stage 1 partial sums ----------------
__global__ __launch_bounds__(256) void k_stats_partial(const float* __restrict__ in,
    float* __restrict__ part, int C, int plane, int NB) {
  int c = blockIdx.x / NB, blk = blockIdx.x % NB;
  int tid = threadIdx.x;
  int N = BB * plane;
  float s = 0.f, q = 0.f;
  for (int i = blk * 256 + tid; i < N; i += NB * 256) {
    int b = i / plane, p = i - b * plane;
    float v = in[(b * C + c) * plane + p];
    s += v; q += v * v;
  }
  __shared__ float ss[256], qq[256];
  ss[tid] = s; qq[tid] = q;
  __syncthreads();
  for (int st = 128; st > 0; st >>= 1) {
    if (tid < st) { ss[tid] += ss[tid + st]; qq[tid] += qq[tid + st]; }
    __syncthreads();
  }
  if (tid == 0) { part[(c * NB + blk) * 2] = ss[0]; part[(c * NB + blk) * 2 + 1] = qq[0]; }
}

// ---------------- batch stats stage 2: scale/shift ----------------
__global__ void k_stats_final(const float* __restrict__ part, const float* __restrict__ g,
    const float* __restrict__ bb, float* __restrict__ sc, float* __restrict__ sh,
    int C, int NB, float invN) {
  int c = blockIdx.x * 64 + threadIdx.x;
  if (c >= C) return;
  float s = 0.f, q = 0.f;
  for (int i = 0; i < NB; i++) { s += part[(c * NB + i) * 2]; q += part[(c * NB + i) * 2 + 1]; }
  float mean = s * invN;
  float var = q * invN - mean * mean;
  var = fmaxf(var, 0.f);
  float scale = g[c] / sqrtf(var + 1e-5f);
  sc[c] = scale; sh[c] = bb[c] - mean * scale;
}

// ---------------- batch stats (96x96 maps): one block per channel ----------------
__global__ __launch_bounds__(256) void k_stats_small(const float* __restrict__ in,
    const float* __restrict__ g, const float* __restrict__ bb,
    float* __restrict__ sc, float* __restrict__ sh, int C) {
  int c = blockIdx.x, tid = threadIdx.x;
  const int N = BB * PLANE_A;                       // 18432 = 72*256 exact
  float s = 0.f, q = 0.f;
  for (int i = tid; i < N; i += 256) {
    int b = i / PLANE_A, p = i - b * PLANE_A;
    float v = in[(b * C + c) * PLANE_A + p];
    s += v; q += v * v;
  }
  __shared__ float ss[256], qq[256];
  ss[tid] = s; qq[tid] = q;
  __syncthreads();
  for (int st = 128; st > 0; st >>= 1) {
    if (tid < st) { ss[tid] += ss[tid + st]; qq[tid] += qq[tid + st]; }
    __syncthreads();
  }
  if (tid == 0) {
    float mean = ss[0] / (float)N;
    float var = qq[0] / (float)N - mean * mean;
    var = fmaxf(var, 0.f);
    float scale = g[c] / sqrtf(var + 1e-5f);
    sc[c] = scale; sh[c] = bb[c] - mean * scale;
  }
}

// ---------------- BuildCost: disp_shift folded into grouped stride-9 conv ----------------
// grid (18, 9, 2); block 256; each thread 2 positions x 16 output channels
__global__ __launch_bounds__(256) void k_buildcost(const float* __restrict__ f,
    const float* __restrict__ sc, const float* __restrict__ sh,
    const float* __restrict__ w, float* __restrict__ cv) {
  __shared__ float wl[9072];                        // [c][u][v][o16]
  __shared__ float scl[7], shl[7];
  int g = blockIdx.y, b = blockIdx.z, tid = threadIdx.x;
  for (int k = tid; k < 9072; k += 256) {
    int o = k & 15; int r = k >> 4;
    int v = r % 9; r /= 9; int u = r % 9; int c = r / 9;
    wl[k] = w[((g * 16 + o) * 7 + c) * 81 + u * 9 + v];
  }
  if (tid < 7) { scl[tid] = sc[tid]; shl[tid] = sh[tid]; }
  __syncthreads();
  int d = g - 4;
  int dil, pad;
  if (d < 0)      { dil = -d * 9 + 1; pad = -36 * d; }
  else if (d == 0){ dil = 1; pad = 0; }
  else            { dil = d * 9 - 1; pad = 36 * d - 8; }
  int p0 = blockIdx.x * 512 + tid;
  int p1 = p0 + 256;
  int i0 = p0 / HH, j0 = p0 - i0 * HH;
  int i1 = p1 / HH, j1 = p1 - i1 * HH;
  int iw0[9], iw1[9];
  #pragma unroll
  for (int k = 0; k < 9; k++) {
    int t0 = j0 * 9 + k * dil - pad; iw0[k] = ((unsigned)t0 < (unsigned)HUV) ? t0 : -1;
    int t1 = j1 * 9 + k * dil - pad; iw1[k] = ((unsigned)t1 < (unsigned)HUV) ? t1 : -1;
  }
  float acc0[16], acc1[16];
  #pragma unroll
  for (int o = 0; o < 16; o++) { acc0[o] = 0.f; acc1[o] = 0.f; }
  for (int c = 0; c < 7; c++) {
    const float* fp = f + (b * 7 + c) * PLANE_F;
    float s = scl[c], h2 = shl[c];
    #pragma unroll
    for (int u = 0; u < 9; u++) {
      int th0 = i0 * 9 + u * dil - pad; bool h0 = (unsigned)th0 < (unsigned)HUV;
      int th1 = i1 * 9 + u * dil - pad; bool h1 = (unsigned)th1 < (unsigned)HUV;
      const float* r0 = fp + th0 * HUV;
      const float* r1 = fp + th1 * HUV;
      const float* wbase = &wl[(c * 9 + u) * 9 * 16];
      #pragma unroll
      for (int v = 0; v < 9; v++) {
        float a0 = 0.f, a1 = 0.f;
        if (h0 && iw0[v] >= 0) a0 = fmaxf(fmaf(r0[iw0[v]], s, h2), 0.f);
        if (h1 && iw1[v] >= 0) a1 = fmaxf(fmaf(r1[iw1[v]], s, h2), 0.f);
        const float* wv = wbase + v * 16;
        #pragma unroll
        for (int o = 0; o < 16; o++) {
          acc0[o] = fmaf(wv[o], a0, acc0[o]);
          acc1[o] = fmaf(wv[o], a1, acc1[o]);
        }
      }
    }
  }
  int cvb = (b * 144 + g * 16) * PLANE_A;
  #pragma unroll
  for (int o = 0; o < 16; o++) {
    cv[cvb + o * PLANE_A + p0] = acc0[o];
    cv[cvb + o * PLANE_A + p1] = acc1[o];
  }
}

// ---------------- depthwise 3x3 pad=1, optional fused input BN+ReLU ----------------
template<bool AFF>
__global__ __launch_bounds__(256) void k_dwconv(const float* __restrict__ in,
    const float* __restrict__ w, const float* __restrict__ isc, const float* __restrict__ ish,
    float* __restrict__ out, int C) {
  int t = blockIdx.x * 256 + threadIdx.x;           // BB*C*9216 exact multiple of 256
  int j = t % HH; int r = t / HH; int i = r % HH; r /= HH; int c = r % C; int b = r / C;
  float s  = AFF ? isc[c] : 1.f;
  float h2 = AFF ? ish[c] : 0.f;
  const float* ip = in + (b * C + c) * PLANE_A;
  float acc = 0.f;
  #pragma unroll
  for (int ky = 0; ky < 3; ky++) {
    int ii = i + ky - 1;
    if ((unsigned)ii >= (unsigned)HH) continue;
    #pragma unroll
    for (int kx = 0; kx < 3; kx++) {
      int jj = j + kx - 1;
      if ((unsigned)jj >= (unsigned)HH) continue;
      float v = ip[ii * HH + jj];
      if (AFF) v = fmaxf(fmaf(v, s, h2), 0.f);
      acc = fmaf(w[c * 9 + ky * 3 + kx], v, acc);
    }
  }
  out[t] = acc;
}

// ---------------- pointwise conv (GEMM), fused input BN+ReLU during staging ----------------
#define PW_TP 64
#define PW_TO 192
#define PW_KC 36
template<int K>
__global__ __launch_bounds__(256) void k_pwconv(const float* __restrict__ in,
    const float* __restrict__ sc, const float* __restrict__ sh,
    const float* __restrict__ w, float* __restrict__ out, int O) {
  __shared__ float xs[PW_KC][PW_TP];
  __shared__ float ws[PW_KC][PW_TO];
  __shared__ float scl[K], shl[K];
  int tid = threadIdx.x;
  for (int c = tid; c < K; c += 256) { scl[c] = sc[c]; shl[c] = sh[c]; }
  __syncthreads();
  int tile = blockIdx.x;                            // BB*9216/64 = 288
  int p0 = tile * PW_TP;
  int b = p0 / PLANE_A;
  int pp0 = p0 - b * PLANE_A;
  int tx = tid % 16, ty = tid / 16;
  float acc[4][12];
  #pragma unroll
  for (int q = 0; q < 4; q++)
    #pragma unroll
    for (int o = 0; o < 12; o++) acc[q][o] = 0.f;
  for (int k0 = 0; k0 < K; k0 += PW_KC) {
    for (int idx = tid; idx < PW_KC * PW_TP; idx += 256) {
      int kk = idx / PW_TP, p = idx - kk * PW_TP;
      int c = k0 + kk;
      float v = in[(b * K + c) * PLANE_A + pp0 + p];
      xs[kk][p] = fmaxf(fmaf(v, scl[c], shl[c]), 0.f);
    }
    for (int idx = tid; idx < PW_KC * PW_TO; idx += 256) {
      int kk = idx / PW_TO, o = idx - kk * PW_TO;
      ws[kk][o] = (o < O) ? w[o * K + k0 + kk] : 0.f;
    }
    __syncthreads();
    #pragma unroll 4
    for (int kk = 0; kk < PW_KC; kk++) {
      float x0 = xs[kk][tx * 4 + 0], x1 = xs[kk][tx * 4 + 1];
      float x2 = xs[kk][tx * 4 + 2], x3 = xs[kk][tx * 4 + 3];
      const float* wr = &ws[kk][ty * 12];
      #pragma unroll
      for (int o = 0; o < 12; o++) {
        float wv = wr[o];
        acc[0][o] = fmaf(x0, wv, acc[0][o]);
        acc[1][o] = fmaf(x1, wv, acc[1][o]);
        acc[2][o] = fmaf(x2, wv, acc[2][o]);
        acc[3][o] = fmaf(x3, wv, acc[3][o]);
      }
    }
    __syncthreads();
  }
  #pragma unroll
  for (int o = 0; o < 12; o++) {
    int oo = ty * 12 + o;
    if (oo < O) {
      float* op = out + (b * O + oo) * PLANE_A + pp0 + tx * 4;
      op[0] = acc[0][o]; op[1] = acc[1][o]; op[2] = acc[2][o]; op[3] = acc[3][o];
    }
  }
}

// ---------------- final: 1x1 conv 180->9 + softmax + disparity expectation ----------------
__global__ __launch_bounds__(256) void k_final(const float* __restrict__ in,
    const float* __restrict__ sc, const float* __restrict__ sh,
    const float* __restrict__ w, float* __restrict__ out) {
  __shared__ float wl[9 * 180];
  __shared__ float scl[180], shl[180];
  int tid = threadIdx.x;
  for (int k = tid; k < 1620; k += 256) wl[k] = w[k];
  for (int c = tid; c < 180; c += 256) { scl[c] = sc[c]; shl[c] = sh[c]; }
  __syncthreads();
  int t = blockIdx.x * 256 + tid;                   // 18432 = 72*256 exact
  int b = t / PLANE_A, p = t - b * PLANE_A;
  float acc[9];
  #pragma unroll
  for (int o = 0; o < 9; o++) acc[o] = 0.f;
  for (int c = 0; c < 180; c++) {
    float v = fmaxf(fmaf(in[(b * 180 + c) * PLANE_A + p], scl[c], shl[c]), 0.f);
    #pragma unroll
    for (int o = 0; o < 9; o++) acc[o] = fmaf(wl[o * 180 + c], v, acc[o]);
  }
  float m = acc[0];
  #pragma unroll
  for (int o = 1; o < 9; o++) m = fmaxf(m, acc[o]);
  float se = 0.f, num = 0.f;
  #pragma unroll
  for (int o = 0; o < 9; o++) {
    float e = expf(acc[o] - m);
    se += e;
    num += (float)(o - 4) * e;
  }
  out[t] = num / se;
}

extern "C" void kernel_launch(void* const* d_in, const int* in_sizes, int n_in,
                              void* d_out, int out_size, void* d_ws, size_t ws_size,
                              hipStream_t stream) {
  const float* x    = (const float*)d_in[0];
  const float* fw0  = (const float*)d_in[1];
  const float* fg0  = (const float*)d_in[2];
  const float* fb0  = (const float*)d_in[3];
  const float* fw   = (const float*)d_in[4];
  const float* fg   = (const float*)d_in[5];
  const float* fb   = (const float*)d_in[6];
  const float* bcw  = (const float*)d_in[7];
  const float* a0dw = (const float*)d_in[8];
  const float* a0dg = (const float*)d_in[9];
  const float* a0db = (const float*)d_in[10];
  const float* a0pw = (const float*)d_in[11];
  const float* a0pg = (const float*)d_in[12];
  const float* a0pb = (const float*)d_in[13];
  const float* amdw = (const float*)d_in[14];
  const float* amdg = (const float*)d_in[15];
  const float* amdb = (const float*)d_in[16];
  const float* ampw = (const float*)d_in[17];
  const float* ampg = (const float*)d_in[18];
  const float* ampb = (const float*)d_in[19];
  const float* ldw  = (const float*)d_in[20];
  const float* ldg  = (const float*)d_in[21];
  const float* ldb  = (const float*)d_in[22];
  const float* lpw  = (const float*)d_in[23];
  float* outp = (float*)d_out;

  // workspace layout (floats): FA, FB (2x 10450944), CV (2654208, aliases MACPI),
  // GA, GB (2x 3317760), PART (23040), SC/SH (180 each) ~= 121 MB
  float* FA    = (float*)d_ws;
  float* FB    = FA + BB * 7 * PLANE_F;
  float* CV    = FB + BB * 7 * PLANE_F;
  float* MACPI = CV;                                 // lifetime-disjoint alias
  float* GA    = CV + BB * 144 * PLANE_A;
  float* GB    = GA + BB * 180 * PLANE_A;
  float* PART  = GB + BB * 180 * PLANE_A;
  float* SC    = PART + 180 * 64 * 2;
  float* SH    = SC + 180;

  const int nthread_f = BB * PLANE_F;                // 1492992
  const int nblk_f = nthread_f / 256;                // 5832

  // 1) MacPI rearrange
  k_macpi<<<nblk_f, 256, 0, stream>>>(x, MACPI);

  // 2) feature extraction: conv0 (1->7) then 6x (7->7), BN fused into consumer reads
  k_featconv<1, 7, false><<<nblk_f, 256, 0, stream>>>(MACPI, fw0, nullptr, nullptr, FA);
  k_stats_partial<<<7 * 64, 256, 0, stream>>>(FA, PART, 7, PLANE_F, 64);
  k_stats_final<<<1, 64, 0, stream>>>(PART, fg0, fb0, SC, SH, 7, 64, 1.0f / (float)(BB * PLANE_F));

  float* cur = FA; float* nxt = FB;
  for (int i = 0; i < 6; i++) {
    k_featconv<7, 7, true><<<nblk_f, 256, 0, stream>>>(cur, fw + i * 441, SC, SH, nxt);
    k_stats_partial<<<7 * 64, 256, 0, stream>>>(nxt, PART, 7, PLANE_F, 64);
    k_stats_final<<<1, 64, 0, stream>>>(PART, fg + i * 7, fb + i * 7, SC, SH, 7, 64,
                                        1.0f / (float)(BB * PLANE_F));
    float* tmp = cur; cur = nxt; nxt = tmp;
  }

  // 3) BuildCost (disp_shift folded in), consumes final feature w/ fused BN+ReLU
  k_buildcost<<<dim3(18, 9, 2), 256, 0, stream>>>(cur, SC, SH, bcw, CV);

  // 4) aggregation
  k_dwconv<false><<<BB * 144 * PLANE_A / 256, 256, 0, stream>>>(CV, a0dw, nullptr, nullptr, GA, 144);
  k_stats_small<<<144, 256, 0, stream>>>(GA, a0dg, a0db, SC, SH, 144);
  k_pwconv<144><<<288, 256, 0, stream>>>(GA, SC, SH, a0pw, GB, 180);
  k_stats_small<<<180, 256, 0, stream>>>(GB, a0pg, a0pb, SC, SH, 180);

  for (int m = 0; m < 4; m++) {
    k_dwconv<true><<<BB * 180 * PLANE_A / 256, 256, 0, stream>>>(GB, amdw + m * 1620, SC, SH, GA, 180);
    k_stats_small<<<180, 256, 0, stream>>>(GA, amdg + m * 180, amdb + m * 180, SC, SH, 180);
    k_pwconv<180><<<288, 256, 0, stream>>>(GA, SC, SH, ampw + m * 32400, GB, 180);
    k_stats_small<<<180, 256, 0, stream>>>(GB, ampg + m * 180, ampb + m * 180, SC, SH, 180);
  }

  k_dwconv<true><<<BB * 180 * PLANE_A / 256, 256, 0, stream>>>(GB, ldw, SC, SH, GA, 180);
  k_stats_small<<<180, 256, 0, stream>>>(GA, ldg, ldb, SC, SH, 180);

  // 5) final 1x1 + softmax + expectation
  k_final<<<72, 256, 0, stream>>>(GA, SC, SH, lpw, outp);
}